// Round 11
// baseline (91.129 us; speedup 1.0000x reference)
//
#include <hip/hip_runtime.h>
#include <hip/hip_bf16.h>

#define NPTS 4096
#define NROWS 8192   // B*N
#define DIM 128
#define GEMM_BLOCKS 1024   // 4096 16x16 tiles / 4 waves

typedef __attribute__((ext_vector_type(8))) short bf16x8;
typedef __attribute__((ext_vector_type(4))) float f32x4;

// ---------- K1: fused pos-repack + xW GEMM (R7-verified) ----------
__global__ __launch_bounds__(256) void k1_prep_gemm(const float* __restrict__ x,
                                                    const float* __restrict__ pos,
                                                    const float* __restrict__ W,
                                                    float4* __restrict__ pos4,
                                                    __hip_bfloat16* __restrict__ xWb) {
    int b = blockIdx.x;
    if (b >= GEMM_BLOCKS) {
        int t = (b - GEMM_BLOCKS) * 256 + threadIdx.x;   // 0..8191
        const float* p = pos + (size_t)t * 3;
        pos4[t] = make_float4(p[0], p[1], p[2], 0.f);
        return;
    }
    int wave = threadIdx.x >> 6;
    int lane = threadIdx.x & 63;
    int tile = b * 4 + wave;                   // 0..4095
    int m0 = (tile >> 3) << 4;
    int n0 = (tile & 7) << 4;
    int r = lane & 15;
    int kg = lane >> 4;                        // 0..3
    const float* xr = x + (size_t)(m0 + r) * DIM + kg * 8;
    const float* wc = W + (size_t)(kg * 8) * DIM + (n0 + r);
    f32x4 acc = {0.f, 0.f, 0.f, 0.f};
    union { __hip_bfloat16 h; short s; } u;
#pragma unroll
    for (int kb = 0; kb < 4; ++kb) {
        float4 a0 = *(const float4*)(xr + kb * 32);
        float4 a1 = *(const float4*)(xr + kb * 32 + 4);
        bf16x8 af, bf;
        u.h = __float2bfloat16(a0.x); af[0] = u.s;
        u.h = __float2bfloat16(a0.y); af[1] = u.s;
        u.h = __float2bfloat16(a0.z); af[2] = u.s;
        u.h = __float2bfloat16(a0.w); af[3] = u.s;
        u.h = __float2bfloat16(a1.x); af[4] = u.s;
        u.h = __float2bfloat16(a1.y); af[5] = u.s;
        u.h = __float2bfloat16(a1.z); af[6] = u.s;
        u.h = __float2bfloat16(a1.w); af[7] = u.s;
#pragma unroll
        for (int i = 0; i < 8; ++i) {
            u.h = __float2bfloat16(wc[(size_t)(kb * 32 + i) * DIM]);
            bf[i] = u.s;
        }
        acc = __builtin_amdgcn_mfma_f32_16x16x32_bf16(af, bf, acc, 0, 0, 0);
    }
    int col = n0 + r;
    int rbase = m0 + (kg << 2);
#pragma unroll
    for (int reg = 0; reg < 4; ++reg)
        xWb[(size_t)(rbase + reg) * DIM + col] = __float2bfloat16(acc[reg]);
}

// ---------- exact f64 packed key: key = f64(d2) with low 12 bits = j ----------
__device__ __forceinline__ double mkkey(float d2, int j) {
    return __longlong_as_double(__double_as_longlong((double)d2) |
                                (unsigned long long)(unsigned)j);
}

// sorted-ascending insert: 7 v_min/max_f64
__device__ __forceinline__ void kins(double& k0, double& k1, double& k2,
                                     double& k3, double s) {
    double c = fmax(k0, s); k0 = fmin(k0, s);
    double t = fmax(k1, c); k1 = fmin(k1, c); c = t;
    t = fmax(k2, c);        k2 = fmin(k2, c); c = t;
    k3 = fmin(k3, c);
}

// merge two sorted-asc 4-lists -> 4 smallest sorted: 12 v_min/max_f64
__device__ __forceinline__ void kmerge(double& a0, double& a1, double& a2,
                                       double& a3, double b0, double b1,
                                       double b2, double b3) {
    double m0 = fmin(a0, b3), m1 = fmin(a1, b2);
    double m2 = fmin(a2, b1), m3 = fmin(a3, b0);
    double t0 = fmin(m0, m2), t2 = fmax(m0, m2);
    double t1 = fmin(m1, m3), t3 = fmax(m1, m3);
    a0 = fmin(t0, t1); a1 = fmax(t0, t1);
    a2 = fmin(t2, t3); a3 = fmax(t2, t3);
}

// ---------- K2: quarter-split topk. Block = 2 rows; each of 4 waves scans
// 1024 candidates (16/lane) for both rows -> per-wave serial chain is half
// of R10's. Cross-wave merge of 4 sorted-4 lists via LDS; wave 0 epilogue.
__global__ __launch_bounds__(256) void topk_agg(const float4* __restrict__ pos4,
                                                const __hip_bfloat16* __restrict__ xWb,
                                                const float* __restrict__ bias,
                                                float* __restrict__ out) {
    int lane = threadIdx.x & 63;
    int wave = threadIdx.x >> 6;               // quarter 0..3
    int rowbase = blockIdx.x * 2;              // 2 rows/block
    int batch = rowbase >> 12;
    int ibase = rowbase & (NPTS - 1);
    const float4* pb = pos4 + (size_t)batch * NPTS;

    float4 q0 = pb[ibase], q1 = pb[ibase + 1];
    const double INF = __builtin_inf();
    double a0 = INF, a1 = INF, a2 = INF, a3 = INF;   // row 0 keys
    double b0 = INF, b1 = INF, b2 = INF, b3 = INF;   // row 1 keys

    int jbase = (wave << 10) + lane;
#pragma unroll 4
    for (int t = 0; t < 16; ++t) {
        int j = jbase + (t << 6);
        float4 p = pb[j];
        float dx = q0.x - p.x, dy = q0.y - p.y, dz = q0.z - p.z;
        float d2 = fmaf(dx, dx, fmaf(dy, dy, dz * dz));
        kins(a0, a1, a2, a3, mkkey(d2, j));
        dx = q1.x - p.x; dy = q1.y - p.y; dz = q1.z - p.z;
        d2 = fmaf(dx, dx, fmaf(dy, dy, dz * dz));
        kins(b0, b1, b2, b3, mkkey(d2, j));
    }

    // intra-wave butterfly: 6 xor steps, bitonic merge each
#pragma unroll
    for (int off = 1; off < 64; off <<= 1) {
        double p0 = __shfl_xor(a0, off), p1 = __shfl_xor(a1, off);
        double p2 = __shfl_xor(a2, off), p3 = __shfl_xor(a3, off);
        kmerge(a0, a1, a2, a3, p0, p1, p2, p3);
        p0 = __shfl_xor(b0, off); p1 = __shfl_xor(b1, off);
        p2 = __shfl_xor(b2, off); p3 = __shfl_xor(b3, off);
        kmerge(b0, b1, b2, b3, p0, p1, p2, p3);
    }

    // cross-wave exchange via LDS (4 quarters x 2 rows x 4 slots)
    __shared__ double lds[4][2][4];
    if (lane == 0) {
        lds[wave][0][0] = a0; lds[wave][0][1] = a1;
        lds[wave][0][2] = a2; lds[wave][0][3] = a3;
        lds[wave][1][0] = b0; lds[wave][1][1] = b1;
        lds[wave][1][2] = b2; lds[wave][1][3] = b3;
    }
    __syncthreads();
    if (wave) return;

#pragma unroll
    for (int qq = 1; qq < 4; ++qq) {
        kmerge(a0, a1, a2, a3, lds[qq][0][0], lds[qq][0][1],
                               lds[qq][0][2], lds[qq][0][3]);
        kmerge(b0, b1, b2, b3, lds[qq][1][0], lds[qq][1][1],
                               lds[qq][1][2], lds[qq][1][3]);
    }

    // epilogue: lane owns channels (2*lane, 2*lane+1)
    int c = lane << 1;
    float2 bb = *(const float2*)(bias + c);
    const unsigned short* xu = (const unsigned short*)xWb;
    size_t bbase = ((size_t)batch * NPTS) << 7;
#pragma unroll
    for (int k = 0; k < 2; ++k) {
        double k0 = k ? b0 : a0, k1 = k ? b1 : a1;
        double k2 = k ? b2 : a2, k3 = k ? b3 : a3;
        unsigned i0 = (unsigned)__double_as_longlong(k0) & 0xFFFu;
        unsigned i1 = (unsigned)__double_as_longlong(k1) & 0xFFFu;
        unsigned i2 = (unsigned)__double_as_longlong(k2) & 0xFFFu;
        unsigned i3 = (unsigned)__double_as_longlong(k3) & 0xFFFu;
        float d0 = (float)k0, d1 = (float)k1, d2 = (float)k2, d3 = (float)k3;
        float w0 = __expf(-(d0 + 1e-8f) * 0.5f);
        float w1 = __expf(-(d1 + 1e-8f) * 0.5f);
        float w2 = __expf(-(d2 + 1e-8f) * 0.5f);
        float w3 = __expf(-(d3 + 1e-8f) * 0.5f);
        float inv = 1.0f / (w0 + w1 + w2 + w3 + 1e-8f);
        w0 *= inv; w1 *= inv; w2 *= inv; w3 *= inv;
        ushort2 g0 = *(const ushort2*)(xu + bbase + ((size_t)i0 << 7) + c);
        ushort2 g1 = *(const ushort2*)(xu + bbase + ((size_t)i1 << 7) + c);
        ushort2 g2 = *(const ushort2*)(xu + bbase + ((size_t)i2 << 7) + c);
        ushort2 g3 = *(const ushort2*)(xu + bbase + ((size_t)i3 << 7) + c);
        float ox = bb.x + w0 * __uint_as_float((unsigned)g0.x << 16)
                        + w1 * __uint_as_float((unsigned)g1.x << 16)
                        + w2 * __uint_as_float((unsigned)g2.x << 16)
                        + w3 * __uint_as_float((unsigned)g3.x << 16);
        float oy = bb.y + w0 * __uint_as_float((unsigned)g0.y << 16)
                        + w1 * __uint_as_float((unsigned)g1.y << 16)
                        + w2 * __uint_as_float((unsigned)g2.y << 16)
                        + w3 * __uint_as_float((unsigned)g3.y << 16);
        *(float2*)(out + (((size_t)(rowbase + k)) << 7) + c) = make_float2(ox, oy);
    }
}

extern "C" void kernel_launch(void* const* d_in, const int* in_sizes, int n_in,
                              void* d_out, int out_size, void* d_ws, size_t ws_size,
                              hipStream_t stream) {
    const float* x    = (const float*)d_in[0];  // [2,4096,128]
    const float* pos  = (const float*)d_in[1];  // [2,4096,3]
    const float* W    = (const float*)d_in[2];  // [128,128]
    const float* bias = (const float*)d_in[3];  // [128]
    float* out = (float*)d_out;                 // [2,4096,128] f32

    char* ws = (char*)d_ws;
    __hip_bfloat16* xWb = (__hip_bfloat16*)ws;                       // 2 MB
    float4* pos4 = (float4*)(ws + (size_t)NROWS * DIM * 2);          // 128 KB

    k1_prep_gemm<<<GEMM_BLOCKS + NROWS / 256, 256, 0, stream>>>(x, pos, W, pos4, xWb);
    topk_agg<<<NROWS / 2, 256, 0, stream>>>(pos4, xWb, bias, out);
}